// Round 1
// baseline (412.027 us; speedup 1.0000x reference)
//
#include <hip/hip_runtime.h>
#include <cmath>

#define NN 100000   // nodes
#define FF 256      // feature dim
#define DDIM 128    // embedding dim
#define MM 10       // categories
#define BB 32768    // batch
#define KK 32       // neighbors

// workspace layout (float offsets), every region fully written before read
#define OFF_FE   0            // [NN][128] flow_emb
#define OFF_Q    12800000     // [NN]      0.5*dot(fe[n], att_w)
#define OFF_PART 12900000     // [256][1280] per-block ce partials
#define OFF_LAT  13227680     // [20][128] sigmoid lat table
#define OFF_WP   13230240     // [128][128] l1w[:128]+l1w[128:]
#define OFF_CE01 13246624     // [2][128] character_emb rows 0,1
#define OFF_CS   13246880     // [2] c0,c1 (0.5*dot(ce_row, att_w))
#define OFF_AGG  13246896     // [BB][128]
// total = 17,441,200 floats = 66.6 MiB

// ---------------------------------------------------------------------------
// fp32 register-blocked GEMM core: C[128 rows][128 cols] per block,
// 256 threads, 8x8 accum/thread, K staged in 64-chunks.
// A-tile stored transposed in LDS with XOR swizzle (col' = r ^ (k&60)) so the
// transpose scatter-writes are 2-way (free) and frag reads stay b128.
// ---------------------------------------------------------------------------
template<int NCHUNK>
__device__ __forceinline__ void gemm_main(const float* __restrict__ A, int lda, int rowclamp,
                                          const float* __restrict__ W,
                                          int rowbase, int tid,
                                          float (*AT)[128], float (*WT)[128],
                                          float (&acc)[8][8])
{
  const int a_r  = tid >> 4;   // 0..15  (row group for A staging)
  const int a_f4 = tid & 15;   // 0..15  (k-chunk float4 for A staging)
  const int w_k  = tid >> 5;   // 0..7
  const int w_f4 = tid & 31;   // 0..31
  const int tx = tid & 15, ty = tid >> 4;

#pragma unroll
  for (int i = 0; i < 8; i++)
#pragma unroll
    for (int j = 0; j < 8; j++) acc[i][j] = 0.f;

  for (int cc = 0; cc < NCHUNK; cc++) {
    const int kc = cc * 64;
    // stage A (transpose + swizzle): rows rowbase..rowbase+127, k kc..kc+63
#pragma unroll
    for (int i = 0; i < 8; i++) {
      int r = a_r + 16 * i;
      int gr = rowbase + r; gr = (gr > rowclamp) ? rowclamp : gr;
      const float4 v = *reinterpret_cast<const float4*>(&A[gr * lda + kc + a_f4 * 4]);
      const int X = a_f4 * 4;          // == (k & 60) for k = X..X+3
      const int col = r ^ X;
      AT[X + 0][col] = v.x;
      AT[X + 1][col] = v.y;
      AT[X + 2][col] = v.z;
      AT[X + 3][col] = v.w;
    }
    // stage W (no transpose needed)
#pragma unroll
    for (int i = 0; i < 8; i++) {
      const int k = w_k + 8 * i;
      *reinterpret_cast<float4*>(&WT[k][w_f4 * 4]) =
          *reinterpret_cast<const float4*>(&W[(kc + k) * 128 + w_f4 * 4]);
    }
    __syncthreads();
#pragma unroll 8
    for (int k = 0; k < 64; k++) {
      const int X = k & 60;
      const float4 va0 = *reinterpret_cast<const float4*>(&AT[k][(ty * 4) ^ X]);
      const float4 va1 = *reinterpret_cast<const float4*>(&AT[k][((ty * 4) ^ X) + 64]);
      const float4 vb0 = *reinterpret_cast<const float4*>(&WT[k][tx * 4]);
      const float4 vb1 = *reinterpret_cast<const float4*>(&WT[k][tx * 4 + 64]);
      const float a[8] = {va0.x, va0.y, va0.z, va0.w, va1.x, va1.y, va1.z, va1.w};
      const float b[8] = {vb0.x, vb0.y, vb0.z, vb0.w, vb1.x, vb1.y, vb1.z, vb1.w};
#pragma unroll
      for (int i = 0; i < 8; i++)
#pragma unroll
        for (int j = 0; j < 8; j++)
          acc[i][j] = fmaf(a[i], b[j], acc[i][j]);
    }
    __syncthreads();
  }
}

// K1: flow_emb = feature @ W_emb + b_emb ; also q[n] = 0.5*dot(fe[n], att_w)
__global__ __launch_bounds__(256) void k1_gemm(const float* __restrict__ feat,
    const float* __restrict__ wemb, const float* __restrict__ bemb,
    const float* __restrict__ attw,
    float* __restrict__ fe, float* __restrict__ q)
{
  __shared__ __align__(16) float AT[64][128];
  __shared__ __align__(16) float WT[64][128];
  const int tid = threadIdx.x;
  const int tx = tid & 15, ty = tid >> 4;
  const int rowbase = blockIdx.x * 128;
  float acc[8][8];
  gemm_main<4>(feat, 256, NN - 1, wemb, rowbase, tid, AT, WT, acc);

  const float4 b0 = *reinterpret_cast<const float4*>(&bemb[tx * 4]);
  const float4 b1 = *reinterpret_cast<const float4*>(&bemb[tx * 4 + 64]);
  const float4 w0 = *reinterpret_cast<const float4*>(&attw[tx * 4]);
  const float4 w1 = *reinterpret_cast<const float4*>(&attw[tx * 4 + 64]);
  const float bb[8] = {b0.x, b0.y, b0.z, b0.w, b1.x, b1.y, b1.z, b1.w};
  const float aw[8] = {w0.x, w0.y, w0.z, w0.w, w1.x, w1.y, w1.z, w1.w};
#pragma unroll
  for (int i = 0; i < 8; i++) {
    const int r = (i < 4) ? (ty * 4 + i) : (64 + ty * 4 + (i - 4));
    const int gr = rowbase + r;
    float v[8]; float qp = 0.f;
#pragma unroll
    for (int j = 0; j < 8; j++) { v[j] = acc[i][j] + bb[j]; qp = fmaf(v[j], aw[j], qp); }
    qp += __shfl_down(qp, 8, 16);
    qp += __shfl_down(qp, 4, 16);
    qp += __shfl_down(qp, 2, 16);
    qp += __shfl_down(qp, 1, 16);
    if (gr < NN) {
      *reinterpret_cast<float4*>(&fe[gr * 128 + tx * 4]) = make_float4(v[0], v[1], v[2], v[3]);
      *reinterpret_cast<float4*>(&fe[gr * 128 + 64 + tx * 4]) = make_float4(v[4], v[5], v[6], v[7]);
      if (tx == 0) q[gr] = 0.5f * qp;
    }
  }
}

// K2: character_emb partials: part[blk][m][d] = sum_{n in chunk} adj[m][n]*fe[n][d]
__global__ __launch_bounds__(512) void k2_char(const float* __restrict__ fe,
    const float* __restrict__ adj, float* __restrict__ part)
{
  __shared__ float cetile[1280];
  const int tid = threadIdx.x;
  const int lane = tid & 63;
  const int sub = tid >> 6;            // 0..7 (wave id) -> n is wave-uniform
  for (int idx = tid; idx < 1280; idx += 512) cetile[idx] = 0.f;
  __syncthreads();

  const int start = blockIdx.x * 391;
  int end = start + 391; if (end > NN) end = NN;
  float2 acc[10];
#pragma unroll
  for (int m = 0; m < 10; m++) { acc[m].x = 0.f; acc[m].y = 0.f; }
  for (int n = start + sub; n < end; n += 8) {
    const int nu = __builtin_amdgcn_readfirstlane(n);   // force scalar adj loads
    const float2 fv = *reinterpret_cast<const float2*>(&fe[nu * 128 + lane * 2]);
#pragma unroll
    for (int m = 0; m < 10; m++) {
      const float a = adj[m * NN + nu];
      acc[m].x = fmaf(a, fv.x, acc[m].x);
      acc[m].y = fmaf(a, fv.y, acc[m].y);
    }
  }
#pragma unroll
  for (int m = 0; m < 10; m++) {
    atomicAdd(&cetile[m * 128 + lane * 2],     acc[m].x);
    atomicAdd(&cetile[m * 128 + lane * 2 + 1], acc[m].y);
  }
  __syncthreads();
  for (int idx = tid; idx < 1280; idx += 512)
    part[blockIdx.x * 1280 + idx] = cetile[idx];
}

// K3: blocks 0..19 -> lat table sigmoid rows; block 20 -> ce rows 0/1, c0/c1, Wp
__global__ __launch_bounds__(128) void k3_prep(const float* __restrict__ part,
    const float* __restrict__ wchar, const float* __restrict__ attw,
    const float* __restrict__ l1w,
    float* __restrict__ latTab, float* __restrict__ Wp,
    float* __restrict__ ce01, float* __restrict__ cs)
{
  const int blk = blockIdx.x, tid = threadIdx.x;
  __shared__ float cec[128], cep[128];
  if (blk < 20) {
    const int c = blk / 10, p = blk % 10;
    float sc_ = 0.f, sp_ = 0.f;
    for (int pp = 0; pp < 256; pp++) {
      sc_ += part[pp * 1280 + c * 128 + tid];
      sp_ += part[pp * 1280 + p * 128 + tid];
    }
    cec[tid] = sc_; cep[tid] = sp_;
    __syncthreads();
    float s = 0.f;
#pragma unroll 4
    for (int j = 0; j < 128; j++) {
      s = fmaf(cec[j], wchar[j * 128 + tid], s);
      s = fmaf(cep[j], wchar[(128 + j) * 128 + tid], s);
    }
    latTab[blk * 128 + tid] = 1.f / (1.f + expf(-s));
  } else {
    float s0 = 0.f, s1 = 0.f;
    for (int pp = 0; pp < 256; pp++) {
      s0 += part[pp * 1280 + tid];
      s1 += part[pp * 1280 + 128 + tid];
    }
    ce01[tid] = s0;
    ce01[128 + tid] = s1;
    cec[tid] = s0 * attw[tid];
    cep[tid] = s1 * attw[tid];
    __syncthreads();
    if (tid < 64) {
      float p0 = cec[tid] + cec[tid + 64];
      float p1 = cep[tid] + cep[tid + 64];
#pragma unroll
      for (int off = 32; off >= 1; off >>= 1) {
        p0 += __shfl_xor(p0, off);
        p1 += __shfl_xor(p1, off);
      }
      if (tid == 0) { cs[0] = 0.5f * p0; cs[1] = 0.5f * p1; }
    }
    for (int i = 0; i < 128; i++)
      Wp[i * 128 + tid] = l1w[i * 128 + tid] + l1w[16384 + i * 128 + tid];
  }
}

// K4a: per-b softmax over 32 neighbor scores + weighted row gather -> agg[b][128]
__global__ __launch_bounds__(256, 4) void k4a_attn(const float* __restrict__ fe,
    const float* __restrict__ q, const float* __restrict__ adj,
    const int* __restrict__ history, const float* __restrict__ cs,
    const float* __restrict__ attb_p, const float* __restrict__ ce01,
    float* __restrict__ agg)
{
  __shared__ float s_att[2][32];
  __shared__ int   s_n[2][32];
  __shared__ float s_s01[2][2];
  const int tid = threadIdx.x;
  const int half = tid >> 7;          // two b's per block
  const int t = tid & 127;
  const int b = blockIdx.x * 2 + half;
  if (t < 32) {                        // lanes 0..31 of a wave: lockstep segment
    const int n = history[b * 32 + t];
    const float a0 = adj[n];
    const float a1 = adj[NN + n];
    const float sc = q[n] + a0 * cs[0] + a1 * cs[1] + attb_p[0];
    float m = sc;
#pragma unroll
    for (int off = 16; off >= 1; off >>= 1) m = fmaxf(m, __shfl_xor(m, off, 32));
    const float e = expf(sc - m);
    float sum = e;
#pragma unroll
    for (int off = 16; off >= 1; off >>= 1) sum += __shfl_xor(sum, off, 32);
    const float att = e / sum;
    s_att[half][t] = att;
    s_n[half][t] = n;
    float p0 = att * a0, p1 = att * a1;
#pragma unroll
    for (int off = 16; off >= 1; off >>= 1) {
      p0 += __shfl_xor(p0, off, 32);
      p1 += __shfl_xor(p1, off, 32);
    }
    if (t == 0) { s_s01[half][0] = p0; s_s01[half][1] = p1; }
  }
  __syncthreads();
  float acc = 0.f;
#pragma unroll 8
  for (int k = 0; k < 32; k++)
    acc = fmaf(s_att[half][k], fe[s_n[half][k] * 128 + t], acc);
  agg[b * 128 + t] = 0.5f * (acc + s_s01[half][0] * ce01[t] + s_s01[half][1] * ce01[128 + t]);
}

// K4b: out = relu(agg @ Wp + l1b); pred_r/pred_n = dot(latTab rows, out)
__global__ __launch_bounds__(256) void k4b_out(const float* __restrict__ agg,
    const float* __restrict__ Wp, const float* __restrict__ l1b,
    const float* __restrict__ latTab,
    const int* __restrict__ cr, const int* __restrict__ cn, const int* __restrict__ pa,
    float* __restrict__ out)
{
  __shared__ __align__(16) float AT[64][128];
  __shared__ __align__(16) float WT[64][128];
  const int tid = threadIdx.x;
  const int tx = tid & 15, ty = tid >> 4;
  const int rowbase = blockIdx.x * 128;
  float acc[8][8];
  gemm_main<2>(agg, 128, BB - 1, Wp, rowbase, tid, AT, WT, acc);

  // reuse LDS (safe: gemm_main ends with __syncthreads) for lat row offsets
  int* latIdx = reinterpret_cast<int*>(&AT[0][0]);
  if (tid < 128) {
    const int b = rowbase + tid;
    latIdx[tid * 2]     = (cr[b] * 10 + pa[b]) * 128;
    latIdx[tid * 2 + 1] = (cn[b] * 10 + pa[b]) * 128;
  }
  __syncthreads();

  const float4 b0 = *reinterpret_cast<const float4*>(&l1b[tx * 4]);
  const float4 b1 = *reinterpret_cast<const float4*>(&l1b[tx * 4 + 64]);
  const float bb[8] = {b0.x, b0.y, b0.z, b0.w, b1.x, b1.y, b1.z, b1.w};
#pragma unroll
  for (int i = 0; i < 8; i++) {
    const int r = (i < 4) ? (ty * 4 + i) : (64 + ty * 4 + (i - 4));
    const int b = rowbase + r;
    const int ir = latIdx[r * 2], in_ = latIdx[r * 2 + 1];
    const float4 lr0 = *reinterpret_cast<const float4*>(&latTab[ir + tx * 4]);
    const float4 lr1 = *reinterpret_cast<const float4*>(&latTab[ir + tx * 4 + 64]);
    const float4 ln0 = *reinterpret_cast<const float4*>(&latTab[in_ + tx * 4]);
    const float4 ln1 = *reinterpret_cast<const float4*>(&latTab[in_ + tx * 4 + 64]);
    const float lr[8] = {lr0.x, lr0.y, lr0.z, lr0.w, lr1.x, lr1.y, lr1.z, lr1.w};
    const float ln[8] = {ln0.x, ln0.y, ln0.z, ln0.w, ln1.x, ln1.y, ln1.z, ln1.w};
    float pr = 0.f, pn = 0.f;
#pragma unroll
    for (int j = 0; j < 8; j++) {
      const float v = fmaxf(acc[i][j] + bb[j], 0.f);
      pr = fmaf(v, lr[j], pr);
      pn = fmaf(v, ln[j], pn);
    }
    pr += __shfl_down(pr, 8, 16); pr += __shfl_down(pr, 4, 16);
    pr += __shfl_down(pr, 2, 16); pr += __shfl_down(pr, 1, 16);
    pn += __shfl_down(pn, 8, 16); pn += __shfl_down(pn, 4, 16);
    pn += __shfl_down(pn, 2, 16); pn += __shfl_down(pn, 1, 16);
    if (tx == 0) { out[b] = pr; out[BB + b] = pn; }
  }
}

extern "C" void kernel_launch(void* const* d_in, const int* in_sizes, int n_in,
                              void* d_out, int out_size, void* d_ws, size_t ws_size,
                              hipStream_t stream) {
  const float* feat  = (const float*)d_in[0];   // [N,F]
  const float* adj   = (const float*)d_in[1];   // [M,N]
  const int*   hist  = (const int*)d_in[2];     // [B,K]
  // d_in[3] item_id unused by reference
  const int*   cr    = (const int*)d_in[4];
  const int*   cn    = (const int*)d_in[5];
  const int*   pa    = (const int*)d_in[6];
  const float* wemb  = (const float*)d_in[7];   // [F,D]
  const float* bemb  = (const float*)d_in[8];   // [D]
  const float* wchar = (const float*)d_in[9];   // [2D,D]
  const float* attw  = (const float*)d_in[10];  // [D]
  const float* attb  = (const float*)d_in[11];  // [1]
  const float* l1w   = (const float*)d_in[12];  // [2D,D]
  const float* l1b   = (const float*)d_in[13];  // [D]
  float* out = (float*)d_out;
  float* ws  = (float*)d_ws;

  float* fe   = ws + OFF_FE;
  float* q    = ws + OFF_Q;
  float* part = ws + OFF_PART;
  float* lat  = ws + OFF_LAT;
  float* Wp   = ws + OFF_WP;
  float* ce01 = ws + OFF_CE01;
  float* cs   = ws + OFF_CS;
  float* agg  = ws + OFF_AGG;

  k1_gemm<<<782, 256, 0, stream>>>(feat, wemb, bemb, attw, fe, q);
  k2_char<<<256, 512, 0, stream>>>(fe, adj, part);
  k3_prep<<<21, 128, 0, stream>>>(part, wchar, attw, l1w, lat, Wp, ce01, cs);
  k4a_attn<<<16384, 256, 0, stream>>>(fe, q, adj, hist, cs, attb, ce01, agg);
  k4b_out<<<256, 256, 0, stream>>>(agg, Wp, l1b, lat, cr, cn, pa, out);
}

// Round 2
// 376.593 us; speedup vs baseline: 1.0941x; 1.0941x over previous
//
#include <hip/hip_runtime.h>
#include <cmath>

#define NN 100000   // nodes
#define FF 256      // feature dim
#define DDIM 128    // embedding dim
#define MM 10       // categories
#define BB 32768    // batch
#define KK 32       // neighbors

// workspace layout (float offsets), every region fully written before read
#define OFF_FE   0            // [NN][128] flow_emb
#define OFF_Q    12800000     // [NN]      0.5*dot(fe[n], att_w)
#define OFF_PART 12900000     // [256][1280] per-block ce partials (k2->k3)
                              //   ALIASED early by k0/k1 as W-frag hi/lo (64K shorts
                              //   = 32768 floats); k1 finishes before k2 writes part.
#define OFF_LAT  13227680     // [20][128] sigmoid lat table
#define OFF_WP   13230240     // [128][128] l1w[:128]+l1w[128:]
#define OFF_CE01 13246624     // [2][128] character_emb rows 0,1
#define OFF_CS   13246880     // [2] c0,c1 (0.5*dot(ce_row, att_w))
#define OFF_AGG  13246896     // [BB][128]
// total = 17,441,200 floats = 66.6 MiB

typedef __attribute__((ext_vector_type(8))) short bf16x8;
typedef __attribute__((ext_vector_type(4))) float floatx4;

__device__ __forceinline__ unsigned short f2bf(float x) {
  union { float f; unsigned u; } v; v.f = x;
  unsigned r = v.u + 0x7FFFu + ((v.u >> 16) & 1u);   // RNE
  return (unsigned short)(r >> 16);
}
__device__ __forceinline__ float bf2f(unsigned short h) {
  union { float f; unsigned u; } v; v.u = ((unsigned)h) << 16;
  return v.f;
}

// ---------------------------------------------------------------------------
// k0: convert W_emb [256][128] fp32 -> fragment-linear bf16 hi/lo for the
// 16x16x32 MFMA B-operand: wf[h][kk][ct][lane][j] (shorts), h=0 hi, h=1 lo.
// element = W[kk*32 + (lane>>4)*8 + j][ct*16 + (lane&15)]
// ---------------------------------------------------------------------------
__global__ __launch_bounds__(256) void k0_wprep(const float* __restrict__ wemb,
                                                short* __restrict__ wf)
{
  const int t = blockIdx.x * 256 + threadIdx.x;   // 0..4095
  const int kk = t >> 9, rem = t & 511;
  const int ct = rem >> 6, l = rem & 63;
  const int n = ct * 16 + (l & 15);
  const int kbase = kk * 32 + (l >> 4) * 8;
  short hi[8], lo[8];
#pragma unroll
  for (int j = 0; j < 8; j++) {
    const float x = wemb[(kbase + j) * 128 + n];
    const unsigned short h = f2bf(x);
    hi[j] = (short)h;
    lo[j] = (short)f2bf(x - bf2f(h));
  }
  const int off = ((kk * 8 + ct) * 64 + l) * 8;
  *reinterpret_cast<int4*>(&wf[off])         = *reinterpret_cast<int4*>(hi);
  *reinterpret_cast<int4*>(&wf[32768 + off]) = *reinterpret_cast<int4*>(lo);
}

__device__ __forceinline__ void split8(const float* __restrict__ p,
                                       bf16x8& hi8, bf16x8& lo8)
{
  const float4 a = *reinterpret_cast<const float4*>(p);
  const float4 b = *reinterpret_cast<const float4*>(p + 4);
  const float xs[8] = {a.x, a.y, a.z, a.w, b.x, b.y, b.z, b.w};
  short h[8], l[8];
#pragma unroll
  for (int j = 0; j < 8; j++) {
    const unsigned short hh = f2bf(xs[j]);
    h[j] = (short)hh;
    l[j] = (short)f2bf(xs[j] - bf2f(hh));
  }
  hi8 = *reinterpret_cast<bf16x8*>(h);
  lo8 = *reinterpret_cast<bf16x8*>(l);
}

// ---------------------------------------------------------------------------
// K1: fe = feature @ W_emb + b_emb via split-bf16 MFMA (3 products: hh, hl, lh)
//     + q[n] = 0.5*dot(fe[n], att_w) fused in epilogue.
// 256 thr = 4 waves; wave w does rows [blk*128+32w, +32): 2 row-tiles x 8
// col-tiles of 16x16x32. A loaded global->reg (no LDS anywhere).
// ---------------------------------------------------------------------------
__global__ __launch_bounds__(256) void k1_mfma(const float* __restrict__ feat,
    const short* __restrict__ wf, const float* __restrict__ bemb,
    const float* __restrict__ attw,
    float* __restrict__ fe, float* __restrict__ q)
{
  const int tid = threadIdx.x;
  const int wv = tid >> 6, l = tid & 63;
  const int lane16 = l & 15, quad = l >> 4;
  const int rowbase = blockIdx.x * 128 + wv * 32;

  floatx4 acc[2][8];
#pragma unroll
  for (int rt = 0; rt < 2; rt++)
#pragma unroll
    for (int ct = 0; ct < 8; ct++) acc[rt][ct] = floatx4{0.f, 0.f, 0.f, 0.f};

  int r0 = rowbase + lane16;      if (r0 > NN - 1) r0 = NN - 1;
  int r1 = rowbase + 16 + lane16; if (r1 > NN - 1) r1 = NN - 1;
  const float* pa0 = &feat[(size_t)r0 * 256 + quad * 8];
  const float* pa1 = &feat[(size_t)r1 * 256 + quad * 8];

  for (int kk = 0; kk < 8; kk++) {
    bf16x8 a0h, a0l, a1h, a1l;
    split8(pa0 + kk * 32, a0h, a0l);
    split8(pa1 + kk * 32, a1h, a1l);
    const short* wb = &wf[kk * 4096 + l * 8];
#pragma unroll
    for (int ct = 0; ct < 8; ct++) {
      const bf16x8 bh = *reinterpret_cast<const bf16x8*>(&wb[ct * 512]);
      const bf16x8 bl = *reinterpret_cast<const bf16x8*>(&wb[32768 + ct * 512]);
      acc[0][ct] = __builtin_amdgcn_mfma_f32_16x16x32_bf16(a0h, bh, acc[0][ct], 0, 0, 0);
      acc[1][ct] = __builtin_amdgcn_mfma_f32_16x16x32_bf16(a1h, bh, acc[1][ct], 0, 0, 0);
      acc[0][ct] = __builtin_amdgcn_mfma_f32_16x16x32_bf16(a0l, bh, acc[0][ct], 0, 0, 0);
      acc[1][ct] = __builtin_amdgcn_mfma_f32_16x16x32_bf16(a1l, bh, acc[1][ct], 0, 0, 0);
      acc[0][ct] = __builtin_amdgcn_mfma_f32_16x16x32_bf16(a0h, bl, acc[0][ct], 0, 0, 0);
      acc[1][ct] = __builtin_amdgcn_mfma_f32_16x16x32_bf16(a1h, bl, acc[1][ct], 0, 0, 0);
    }
  }

  // epilogue: bias, q-dot, store. C layout: col = ct*16 + lane16,
  // row = rowbase + rt*16 + quad*4 + reg (verified m89/m91).
  float bembv[8], attwv[8];
#pragma unroll
  for (int ct = 0; ct < 8; ct++) {
    bembv[ct] = bemb[ct * 16 + lane16];
    attwv[ct] = attw[ct * 16 + lane16];
  }
#pragma unroll
  for (int rt = 0; rt < 2; rt++) {
#pragma unroll
    for (int reg = 0; reg < 4; reg++) {
      const int r = rowbase + rt * 16 + quad * 4 + reg;
      float v[8]; float qp = 0.f;
#pragma unroll
      for (int ct = 0; ct < 8; ct++) {
        v[ct] = acc[rt][ct][reg] + bembv[ct];
        qp = fmaf(v[ct], attwv[ct], qp);
      }
      qp += __shfl_xor(qp, 1, 16);
      qp += __shfl_xor(qp, 2, 16);
      qp += __shfl_xor(qp, 4, 16);
      qp += __shfl_xor(qp, 8, 16);
      if (r < NN) {
#pragma unroll
        for (int ct = 0; ct < 8; ct++) fe[(size_t)r * 128 + ct * 16 + lane16] = v[ct];
        if (lane16 == 0) q[r] = 0.5f * qp;
      }
    }
  }
}

// ---------------------------------------------------------------------------
// fp32 register-blocked GEMM core (kept for k4b): C[128][128] per block,
// 256 threads, 8x8 accum/thread, K staged in 64-chunks, XOR-swizzled A.
// ---------------------------------------------------------------------------
template<int NCHUNK>
__device__ __forceinline__ void gemm_main(const float* __restrict__ A, int lda, int rowclamp,
                                          const float* __restrict__ W,
                                          int rowbase, int tid,
                                          float (*AT)[128], float (*WT)[128],
                                          float (&acc)[8][8])
{
  const int a_r  = tid >> 4;
  const int a_f4 = tid & 15;
  const int w_k  = tid >> 5;
  const int w_f4 = tid & 31;
  const int tx = tid & 15, ty = tid >> 4;

#pragma unroll
  for (int i = 0; i < 8; i++)
#pragma unroll
    for (int j = 0; j < 8; j++) acc[i][j] = 0.f;

  for (int cc = 0; cc < NCHUNK; cc++) {
    const int kc = cc * 64;
#pragma unroll
    for (int i = 0; i < 8; i++) {
      int r = a_r + 16 * i;
      int gr = rowbase + r; gr = (gr > rowclamp) ? rowclamp : gr;
      const float4 v = *reinterpret_cast<const float4*>(&A[gr * lda + kc + a_f4 * 4]);
      const int X = a_f4 * 4;
      const int col = r ^ X;
      AT[X + 0][col] = v.x;
      AT[X + 1][col] = v.y;
      AT[X + 2][col] = v.z;
      AT[X + 3][col] = v.w;
    }
#pragma unroll
    for (int i = 0; i < 8; i++) {
      const int k = w_k + 8 * i;
      *reinterpret_cast<float4*>(&WT[k][w_f4 * 4]) =
          *reinterpret_cast<const float4*>(&W[(kc + k) * 128 + w_f4 * 4]);
    }
    __syncthreads();
#pragma unroll 8
    for (int k = 0; k < 64; k++) {
      const int X = k & 60;
      const float4 va0 = *reinterpret_cast<const float4*>(&AT[k][(ty * 4) ^ X]);
      const float4 va1 = *reinterpret_cast<const float4*>(&AT[k][((ty * 4) ^ X) + 64]);
      const float4 vb0 = *reinterpret_cast<const float4*>(&WT[k][tx * 4]);
      const float4 vb1 = *reinterpret_cast<const float4*>(&WT[k][tx * 4 + 64]);
      const float a[8] = {va0.x, va0.y, va0.z, va0.w, va1.x, va1.y, va1.z, va1.w};
      const float b[8] = {vb0.x, vb0.y, vb0.z, vb0.w, vb1.x, vb1.y, vb1.z, vb1.w};
#pragma unroll
      for (int i = 0; i < 8; i++)
#pragma unroll
        for (int j = 0; j < 8; j++)
          acc[i][j] = fmaf(a[i], b[j], acc[i][j]);
    }
    __syncthreads();
  }
}

// K2: character_emb partials: part[blk][m][d] = sum_{n in chunk} adj[m][n]*fe[n][d]
__global__ __launch_bounds__(512) void k2_char(const float* __restrict__ fe,
    const float* __restrict__ adj, float* __restrict__ part)
{
  __shared__ float cetile[1280];
  const int tid = threadIdx.x;
  const int lane = tid & 63;
  const int sub = tid >> 6;
  for (int idx = tid; idx < 1280; idx += 512) cetile[idx] = 0.f;
  __syncthreads();

  const int start = blockIdx.x * 391;
  int end = start + 391; if (end > NN) end = NN;
  float2 acc[10];
#pragma unroll
  for (int m = 0; m < 10; m++) { acc[m].x = 0.f; acc[m].y = 0.f; }
  for (int n = start + sub; n < end; n += 8) {
    const int nu = __builtin_amdgcn_readfirstlane(n);
    const float2 fv = *reinterpret_cast<const float2*>(&fe[nu * 128 + lane * 2]);
#pragma unroll
    for (int m = 0; m < 10; m++) {
      const float a = adj[m * NN + nu];
      acc[m].x = fmaf(a, fv.x, acc[m].x);
      acc[m].y = fmaf(a, fv.y, acc[m].y);
    }
  }
#pragma unroll
  for (int m = 0; m < 10; m++) {
    atomicAdd(&cetile[m * 128 + lane * 2],     acc[m].x);
    atomicAdd(&cetile[m * 128 + lane * 2 + 1], acc[m].y);
  }
  __syncthreads();
  for (int idx = tid; idx < 1280; idx += 512)
    part[blockIdx.x * 1280 + idx] = cetile[idx];
}

// K3: blocks 0..19 -> lat table sigmoid rows; block 20 -> ce rows 0/1, c0/c1, Wp
__global__ __launch_bounds__(128) void k3_prep(const float* __restrict__ part,
    const float* __restrict__ wchar, const float* __restrict__ attw,
    const float* __restrict__ l1w,
    float* __restrict__ latTab, float* __restrict__ Wp,
    float* __restrict__ ce01, float* __restrict__ cs)
{
  const int blk = blockIdx.x, tid = threadIdx.x;
  __shared__ float cec[128], cep[128];
  if (blk < 20) {
    const int c = blk / 10, p = blk % 10;
    float sc_ = 0.f, sp_ = 0.f;
    for (int pp = 0; pp < 256; pp++) {
      sc_ += part[pp * 1280 + c * 128 + tid];
      sp_ += part[pp * 1280 + p * 128 + tid];
    }
    cec[tid] = sc_; cep[tid] = sp_;
    __syncthreads();
    float s = 0.f;
#pragma unroll 4
    for (int j = 0; j < 128; j++) {
      s = fmaf(cec[j], wchar[j * 128 + tid], s);
      s = fmaf(cep[j], wchar[(128 + j) * 128 + tid], s);
    }
    latTab[blk * 128 + tid] = 1.f / (1.f + expf(-s));
  } else {
    float s0 = 0.f, s1 = 0.f;
    for (int pp = 0; pp < 256; pp++) {
      s0 += part[pp * 1280 + tid];
      s1 += part[pp * 1280 + 128 + tid];
    }
    ce01[tid] = s0;
    ce01[128 + tid] = s1;
    cec[tid] = s0 * attw[tid];
    cep[tid] = s1 * attw[tid];
    __syncthreads();
    if (tid < 64) {
      float p0 = cec[tid] + cec[tid + 64];
      float p1 = cep[tid] + cep[tid + 64];
#pragma unroll
      for (int off = 32; off >= 1; off >>= 1) {
        p0 += __shfl_xor(p0, off);
        p1 += __shfl_xor(p1, off);
      }
      if (tid == 0) { cs[0] = 0.5f * p0; cs[1] = 0.5f * p1; }
    }
    for (int i = 0; i < 128; i++)
      Wp[i * 128 + tid] = l1w[i * 128 + tid] + l1w[16384 + i * 128 + tid];
  }
}

// K4a: per-b softmax over 32 neighbor scores + weighted row gather -> agg[b][128]
__global__ __launch_bounds__(256, 4) void k4a_attn(const float* __restrict__ fe,
    const float* __restrict__ q, const float* __restrict__ adj,
    const int* __restrict__ history, const float* __restrict__ cs,
    const float* __restrict__ attb_p, const float* __restrict__ ce01,
    float* __restrict__ agg)
{
  __shared__ float s_att[2][32];
  __shared__ int   s_n[2][32];
  __shared__ float s_s01[2][2];
  const int tid = threadIdx.x;
  const int half = tid >> 7;
  const int t = tid & 127;
  const int b = blockIdx.x * 2 + half;
  if (t < 32) {
    const int n = history[b * 32 + t];
    const float a0 = adj[n];
    const float a1 = adj[NN + n];
    const float sc = q[n] + a0 * cs[0] + a1 * cs[1] + attb_p[0];
    float m = sc;
#pragma unroll
    for (int off = 16; off >= 1; off >>= 1) m = fmaxf(m, __shfl_xor(m, off, 32));
    const float e = expf(sc - m);
    float sum = e;
#pragma unroll
    for (int off = 16; off >= 1; off >>= 1) sum += __shfl_xor(sum, off, 32);
    const float att = e / sum;
    s_att[half][t] = att;
    s_n[half][t] = n;
    float p0 = att * a0, p1 = att * a1;
#pragma unroll
    for (int off = 16; off >= 1; off >>= 1) {
      p0 += __shfl_xor(p0, off, 32);
      p1 += __shfl_xor(p1, off, 32);
    }
    if (t == 0) { s_s01[half][0] = p0; s_s01[half][1] = p1; }
  }
  __syncthreads();
  float acc = 0.f;
#pragma unroll 8
  for (int k = 0; k < 32; k++)
    acc = fmaf(s_att[half][k], fe[s_n[half][k] * 128 + t], acc);
  agg[b * 128 + t] = 0.5f * (acc + s_s01[half][0] * ce01[t] + s_s01[half][1] * ce01[128 + t]);
}

// K4b: out = relu(agg @ Wp + l1b); pred_r/pred_n = dot(latTab rows, out)
__global__ __launch_bounds__(256) void k4b_out(const float* __restrict__ agg,
    const float* __restrict__ Wp, const float* __restrict__ l1b,
    const float* __restrict__ latTab,
    const int* __restrict__ cr, const int* __restrict__ cn, const int* __restrict__ pa,
    float* __restrict__ out)
{
  __shared__ __align__(16) float AT[64][128];
  __shared__ __align__(16) float WT[64][128];
  const int tid = threadIdx.x;
  const int tx = tid & 15, ty = tid >> 4;
  const int rowbase = blockIdx.x * 128;
  float acc[8][8];
  gemm_main<2>(agg, 128, BB - 1, Wp, rowbase, tid, AT, WT, acc);

  int* latIdx = reinterpret_cast<int*>(&AT[0][0]);
  if (tid < 128) {
    const int b = rowbase + tid;
    latIdx[tid * 2]     = (cr[b] * 10 + pa[b]) * 128;
    latIdx[tid * 2 + 1] = (cn[b] * 10 + pa[b]) * 128;
  }
  __syncthreads();

  const float4 b0 = *reinterpret_cast<const float4*>(&l1b[tx * 4]);
  const float4 b1 = *reinterpret_cast<const float4*>(&l1b[tx * 4 + 64]);
  const float bb[8] = {b0.x, b0.y, b0.z, b0.w, b1.x, b1.y, b1.z, b1.w};
#pragma unroll
  for (int i = 0; i < 8; i++) {
    const int r = (i < 4) ? (ty * 4 + i) : (64 + ty * 4 + (i - 4));
    const int b = rowbase + r;
    const int ir = latIdx[r * 2], in_ = latIdx[r * 2 + 1];
    const float4 lr0 = *reinterpret_cast<const float4*>(&latTab[ir + tx * 4]);
    const float4 lr1 = *reinterpret_cast<const float4*>(&latTab[ir + tx * 4 + 64]);
    const float4 ln0 = *reinterpret_cast<const float4*>(&latTab[in_ + tx * 4]);
    const float4 ln1 = *reinterpret_cast<const float4*>(&latTab[in_ + tx * 4 + 64]);
    const float lr[8] = {lr0.x, lr0.y, lr0.z, lr0.w, lr1.x, lr1.y, lr1.z, lr1.w};
    const float ln[8] = {ln0.x, ln0.y, ln0.z, ln0.w, ln1.x, ln1.y, ln1.z, ln1.w};
    float pr = 0.f, pn = 0.f;
#pragma unroll
    for (int j = 0; j < 8; j++) {
      const float v = fmaxf(acc[i][j] + bb[j], 0.f);
      pr = fmaf(v, lr[j], pr);
      pn = fmaf(v, ln[j], pn);
    }
    pr += __shfl_down(pr, 8, 16); pr += __shfl_down(pr, 4, 16);
    pr += __shfl_down(pr, 2, 16); pr += __shfl_down(pr, 1, 16);
    pn += __shfl_down(pn, 8, 16); pn += __shfl_down(pn, 4, 16);
    pn += __shfl_down(pn, 2, 16); pn += __shfl_down(pn, 1, 16);
    if (tx == 0) { out[b] = pr; out[BB + b] = pn; }
  }
}

extern "C" void kernel_launch(void* const* d_in, const int* in_sizes, int n_in,
                              void* d_out, int out_size, void* d_ws, size_t ws_size,
                              hipStream_t stream) {
  const float* feat  = (const float*)d_in[0];   // [N,F]
  const float* adj   = (const float*)d_in[1];   // [M,N]
  const int*   hist  = (const int*)d_in[2];     // [B,K]
  // d_in[3] item_id unused by reference
  const int*   cr    = (const int*)d_in[4];
  const int*   cn    = (const int*)d_in[5];
  const int*   pa    = (const int*)d_in[6];
  const float* wemb  = (const float*)d_in[7];   // [F,D]
  const float* bemb  = (const float*)d_in[8];   // [D]
  const float* wchar = (const float*)d_in[9];   // [2D,D]
  const float* attw  = (const float*)d_in[10];  // [D]
  const float* attb  = (const float*)d_in[11];  // [1]
  const float* l1w   = (const float*)d_in[12];  // [2D,D]
  const float* l1b   = (const float*)d_in[13];  // [D]
  float* out = (float*)d_out;
  float* ws  = (float*)d_ws;

  float* fe   = ws + OFF_FE;
  float* q    = ws + OFF_Q;
  float* part = ws + OFF_PART;
  short* wf   = (short*)(ws + OFF_PART);        // aliased; dead before k2 writes part
  float* lat  = ws + OFF_LAT;
  float* Wp   = ws + OFF_WP;
  float* ce01 = ws + OFF_CE01;
  float* cs   = ws + OFF_CS;
  float* agg  = ws + OFF_AGG;

  k0_wprep<<<16, 256, 0, stream>>>(wemb, wf);
  k1_mfma<<<782, 256, 0, stream>>>(feat, wf, bemb, attw, fe, q);
  k2_char<<<256, 512, 0, stream>>>(fe, adj, part);
  k3_prep<<<21, 128, 0, stream>>>(part, wchar, attw, l1w, lat, Wp, ce01, cs);
  k4a_attn<<<16384, 256, 0, stream>>>(fe, q, adj, hist, cs, attb, ce01, agg);
  k4b_out<<<256, 256, 0, stream>>>(agg, Wp, l1b, lat, cr, cn, pa, out);
}

// Round 3
// 335.516 us; speedup vs baseline: 1.2280x; 1.1224x over previous
//
#include <hip/hip_runtime.h>
#include <cmath>

#define NN 100000   // nodes
#define FF 256      // feature dim
#define DDIM 128    // embedding dim
#define MM 10       // categories
#define BB 32768    // batch
#define KK 32       // neighbors

// workspace layout (float offsets), every region fully written before read
#define OFF_FE   0            // [NN][128] flow_emb fp32
#define OFF_Q    12800000     // [NN]      0.5*dot(fe[n], att_w)
#define OFF_PART 12900000     // [256][1280] per-block ce partials (k2->k3)
                              //   ALIASED early by k0/k1 as W-frag hi/lo (64K shorts)
#define OFF_LAT  13227680     // [20][128] sigmoid lat table
#define OFF_WP   13230240     // [128][128] l1w[:128]+l1w[128:]
#define OFF_CE01 13246624     // [2][128] character_emb rows 0,1
#define OFF_CS   13246880     // [2] c0,c1 (0.5*dot(ce_row, att_w))
#define OFF_AGG  13246896     // [BB][128]
#define OFF_FE8  17441200     // [NN][128] bytes fp8 e4m3 copy of fe (3.2M floats)
// total = 20,641,200 floats = 78.7 MiB

typedef __attribute__((ext_vector_type(8))) short bf16x8;
typedef __attribute__((ext_vector_type(4))) float floatx4;
typedef __attribute__((ext_vector_type(2))) float floatx2;

__device__ __forceinline__ unsigned short f2bf(float x) {
  union { float f; unsigned u; } v; v.f = x;
  unsigned r = v.u + 0x7FFFu + ((v.u >> 16) & 1u);   // RNE
  return (unsigned short)(r >> 16);
}
__device__ __forceinline__ float bf2f(unsigned short h) {
  union { float f; unsigned u; } v; v.u = ((unsigned)h) << 16;
  return v.f;
}

// ---------------------------------------------------------------------------
// k0: convert W_emb [256][128] fp32 -> fragment-linear bf16 hi/lo for the
// 16x16x32 MFMA B-operand: wf[h][kk][ct][lane][j] (shorts), h=0 hi, h=1 lo.
// element = W[kk*32 + (lane>>4)*8 + j][ct*16 + (lane&15)]
// ---------------------------------------------------------------------------
__global__ __launch_bounds__(256) void k0_wprep(const float* __restrict__ wemb,
                                                short* __restrict__ wf)
{
  const int t = blockIdx.x * 256 + threadIdx.x;   // 0..4095
  const int kk = t >> 9, rem = t & 511;
  const int ct = rem >> 6, l = rem & 63;
  const int n = ct * 16 + (l & 15);
  const int kbase = kk * 32 + (l >> 4) * 8;
  short hi[8], lo[8];
#pragma unroll
  for (int j = 0; j < 8; j++) {
    const float x = wemb[(kbase + j) * 128 + n];
    const unsigned short h = f2bf(x);
    hi[j] = (short)h;
    lo[j] = (short)f2bf(x - bf2f(h));
  }
  const int off = ((kk * 8 + ct) * 64 + l) * 8;
  *reinterpret_cast<int4*>(&wf[off])         = *reinterpret_cast<int4*>(hi);
  *reinterpret_cast<int4*>(&wf[32768 + off]) = *reinterpret_cast<int4*>(lo);
}

__device__ __forceinline__ void split8(const float* __restrict__ p,
                                       bf16x8& hi8, bf16x8& lo8)
{
  const float4 a = *reinterpret_cast<const float4*>(p);
  const float4 b = *reinterpret_cast<const float4*>(p + 4);
  const float xs[8] = {a.x, a.y, a.z, a.w, b.x, b.y, b.z, b.w};
  short h[8], l[8];
#pragma unroll
  for (int j = 0; j < 8; j++) {
    const unsigned short hh = f2bf(xs[j]);
    h[j] = (short)hh;
    l[j] = (short)f2bf(xs[j] - bf2f(hh));
  }
  hi8 = *reinterpret_cast<bf16x8*>(h);
  lo8 = *reinterpret_cast<bf16x8*>(l);
}

// ---------------------------------------------------------------------------
// K1: fe = feature @ W_emb + b_emb via split-bf16 MFMA (hh, hl, lh)
//     + q[n] = 0.5*dot(fe[n], att_w) + fp8 copy fe8, fused in epilogue.
// ---------------------------------------------------------------------------
__global__ __launch_bounds__(256) void k1_mfma(const float* __restrict__ feat,
    const short* __restrict__ wf, const float* __restrict__ bemb,
    const float* __restrict__ attw,
    float* __restrict__ fe, float* __restrict__ q,
    unsigned char* __restrict__ fe8)
{
  const int tid = threadIdx.x;
  const int wv = tid >> 6, l = tid & 63;
  const int lane16 = l & 15, quad = l >> 4;
  const int rowbase = blockIdx.x * 128 + wv * 32;

  floatx4 acc[2][8];
#pragma unroll
  for (int rt = 0; rt < 2; rt++)
#pragma unroll
    for (int ct = 0; ct < 8; ct++) acc[rt][ct] = floatx4{0.f, 0.f, 0.f, 0.f};

  int r0 = rowbase + lane16;      if (r0 > NN - 1) r0 = NN - 1;
  int r1 = rowbase + 16 + lane16; if (r1 > NN - 1) r1 = NN - 1;
  const float* pa0 = &feat[(size_t)r0 * 256 + quad * 8];
  const float* pa1 = &feat[(size_t)r1 * 256 + quad * 8];

  for (int kk = 0; kk < 8; kk++) {
    bf16x8 a0h, a0l, a1h, a1l;
    split8(pa0 + kk * 32, a0h, a0l);
    split8(pa1 + kk * 32, a1h, a1l);
    const short* wb = &wf[kk * 4096 + l * 8];
#pragma unroll
    for (int ct = 0; ct < 8; ct++) {
      const bf16x8 bh = *reinterpret_cast<const bf16x8*>(&wb[ct * 512]);
      const bf16x8 bl = *reinterpret_cast<const bf16x8*>(&wb[32768 + ct * 512]);
      acc[0][ct] = __builtin_amdgcn_mfma_f32_16x16x32_bf16(a0h, bh, acc[0][ct], 0, 0, 0);
      acc[1][ct] = __builtin_amdgcn_mfma_f32_16x16x32_bf16(a1h, bh, acc[1][ct], 0, 0, 0);
      acc[0][ct] = __builtin_amdgcn_mfma_f32_16x16x32_bf16(a0l, bh, acc[0][ct], 0, 0, 0);
      acc[1][ct] = __builtin_amdgcn_mfma_f32_16x16x32_bf16(a1l, bh, acc[1][ct], 0, 0, 0);
      acc[0][ct] = __builtin_amdgcn_mfma_f32_16x16x32_bf16(a0h, bl, acc[0][ct], 0, 0, 0);
      acc[1][ct] = __builtin_amdgcn_mfma_f32_16x16x32_bf16(a1h, bl, acc[1][ct], 0, 0, 0);
    }
  }

  // epilogue: bias, q-dot, fp32 + fp8 stores. C layout: col = ct*16 + lane16,
  // row = rowbase + rt*16 + quad*4 + reg (verified m89/m91).
  float bembv[8], attwv[8];
#pragma unroll
  for (int ct = 0; ct < 8; ct++) {
    bembv[ct] = bemb[ct * 16 + lane16];
    attwv[ct] = attw[ct * 16 + lane16];
  }
#pragma unroll
  for (int rt = 0; rt < 2; rt++) {
#pragma unroll
    for (int reg = 0; reg < 4; reg++) {
      const int r = rowbase + rt * 16 + quad * 4 + reg;
      float v[8]; float qp = 0.f;
#pragma unroll
      for (int ct = 0; ct < 8; ct++) {
        v[ct] = acc[rt][ct][reg] + bembv[ct];
        qp = fmaf(v[ct], attwv[ct], qp);
      }
      qp += __shfl_xor(qp, 1, 16);
      qp += __shfl_xor(qp, 2, 16);
      qp += __shfl_xor(qp, 4, 16);
      qp += __shfl_xor(qp, 8, 16);
      if (r < NN) {
#pragma unroll
        for (int ct = 0; ct < 8; ct++) {
          fe[(size_t)r * 128 + ct * 16 + lane16] = v[ct];
          const int pk = __builtin_amdgcn_cvt_pk_fp8_f32(v[ct], v[ct], 0, false);
          fe8[(size_t)r * 128 + ct * 16 + lane16] = (unsigned char)(pk & 0xFF);
        }
        if (lane16 == 0) q[r] = 0.5f * qp;
      }
    }
  }
}

// ---------------------------------------------------------------------------
// fp32 register-blocked GEMM core (kept for k4b)
// ---------------------------------------------------------------------------
template<int NCHUNK>
__device__ __forceinline__ void gemm_main(const float* __restrict__ A, int lda, int rowclamp,
                                          const float* __restrict__ W,
                                          int rowbase, int tid,
                                          float (*AT)[128], float (*WT)[128],
                                          float (&acc)[8][8])
{
  const int a_r  = tid >> 4;
  const int a_f4 = tid & 15;
  const int w_k  = tid >> 5;
  const int w_f4 = tid & 31;
  const int tx = tid & 15, ty = tid >> 4;

#pragma unroll
  for (int i = 0; i < 8; i++)
#pragma unroll
    for (int j = 0; j < 8; j++) acc[i][j] = 0.f;

  for (int cc = 0; cc < NCHUNK; cc++) {
    const int kc = cc * 64;
#pragma unroll
    for (int i = 0; i < 8; i++) {
      int r = a_r + 16 * i;
      int gr = rowbase + r; gr = (gr > rowclamp) ? rowclamp : gr;
      const float4 v = *reinterpret_cast<const float4*>(&A[gr * lda + kc + a_f4 * 4]);
      const int X = a_f4 * 4;
      const int col = r ^ X;
      AT[X + 0][col] = v.x;
      AT[X + 1][col] = v.y;
      AT[X + 2][col] = v.z;
      AT[X + 3][col] = v.w;
    }
#pragma unroll
    for (int i = 0; i < 8; i++) {
      const int k = w_k + 8 * i;
      *reinterpret_cast<float4*>(&WT[k][w_f4 * 4]) =
          *reinterpret_cast<const float4*>(&W[(kc + k) * 128 + w_f4 * 4]);
    }
    __syncthreads();
#pragma unroll 8
    for (int k = 0; k < 64; k++) {
      const int X = k & 60;
      const float4 va0 = *reinterpret_cast<const float4*>(&AT[k][(ty * 4) ^ X]);
      const float4 va1 = *reinterpret_cast<const float4*>(&AT[k][((ty * 4) ^ X) + 64]);
      const float4 vb0 = *reinterpret_cast<const float4*>(&WT[k][tx * 4]);
      const float4 vb1 = *reinterpret_cast<const float4*>(&WT[k][tx * 4 + 64]);
      const float a[8] = {va0.x, va0.y, va0.z, va0.w, va1.x, va1.y, va1.z, va1.w};
      const float b[8] = {vb0.x, vb0.y, vb0.z, vb0.w, vb1.x, vb1.y, vb1.z, vb1.w};
#pragma unroll
      for (int i = 0; i < 8; i++)
#pragma unroll
        for (int j = 0; j < 8; j++)
          acc[i][j] = fmaf(a[i], b[j], acc[i][j]);
    }
    __syncthreads();
  }
}

// K2: character_emb partials: part[blk][m][d] = sum_{n in chunk} adj[m][n]*fe[n][d]
__global__ __launch_bounds__(512) void k2_char(const float* __restrict__ fe,
    const float* __restrict__ adj, float* __restrict__ part)
{
  __shared__ float cetile[1280];
  const int tid = threadIdx.x;
  const int lane = tid & 63;
  const int sub = tid >> 6;
  for (int idx = tid; idx < 1280; idx += 512) cetile[idx] = 0.f;
  __syncthreads();

  const int start = blockIdx.x * 391;
  int end = start + 391; if (end > NN) end = NN;
  float2 acc[10];
#pragma unroll
  for (int m = 0; m < 10; m++) { acc[m].x = 0.f; acc[m].y = 0.f; }
  for (int n = start + sub; n < end; n += 8) {
    const int nu = __builtin_amdgcn_readfirstlane(n);
    const float2 fv = *reinterpret_cast<const float2*>(&fe[nu * 128 + lane * 2]);
#pragma unroll
    for (int m = 0; m < 10; m++) {
      const float a = adj[m * NN + nu];
      acc[m].x = fmaf(a, fv.x, acc[m].x);
      acc[m].y = fmaf(a, fv.y, acc[m].y);
    }
  }
#pragma unroll
  for (int m = 0; m < 10; m++) {
    atomicAdd(&cetile[m * 128 + lane * 2],     acc[m].x);
    atomicAdd(&cetile[m * 128 + lane * 2 + 1], acc[m].y);
  }
  __syncthreads();
  for (int idx = tid; idx < 1280; idx += 512)
    part[blockIdx.x * 1280 + idx] = cetile[idx];
}

// K3: blocks 0..19 -> lat table sigmoid rows; block 20 -> ce rows 0/1, c0/c1, Wp
__global__ __launch_bounds__(128) void k3_prep(const float* __restrict__ part,
    const float* __restrict__ wchar, const float* __restrict__ attw,
    const float* __restrict__ l1w,
    float* __restrict__ latTab, float* __restrict__ Wp,
    float* __restrict__ ce01, float* __restrict__ cs)
{
  const int blk = blockIdx.x, tid = threadIdx.x;
  __shared__ float cec[128], cep[128];
  if (blk < 20) {
    const int c = blk / 10, p = blk % 10;
    float sc_ = 0.f, sp_ = 0.f;
    for (int pp = 0; pp < 256; pp++) {
      sc_ += part[pp * 1280 + c * 128 + tid];
      sp_ += part[pp * 1280 + p * 128 + tid];
    }
    cec[tid] = sc_; cep[tid] = sp_;
    __syncthreads();
    float s = 0.f;
#pragma unroll 4
    for (int j = 0; j < 128; j++) {
      s = fmaf(cec[j], wchar[j * 128 + tid], s);
      s = fmaf(cep[j], wchar[(128 + j) * 128 + tid], s);
    }
    latTab[blk * 128 + tid] = 1.f / (1.f + expf(-s));
  } else {
    float s0 = 0.f, s1 = 0.f;
    for (int pp = 0; pp < 256; pp++) {
      s0 += part[pp * 1280 + tid];
      s1 += part[pp * 1280 + 128 + tid];
    }
    ce01[tid] = s0;
    ce01[128 + tid] = s1;
    cec[tid] = s0 * attw[tid];
    cep[tid] = s1 * attw[tid];
    __syncthreads();
    if (tid < 64) {
      float p0 = cec[tid] + cec[tid + 64];
      float p1 = cep[tid] + cep[tid + 64];
#pragma unroll
      for (int off = 32; off >= 1; off >>= 1) {
        p0 += __shfl_xor(p0, off);
        p1 += __shfl_xor(p1, off);
      }
      if (tid == 0) { cs[0] = 0.5f * p0; cs[1] = 0.5f * p1; }
    }
    for (int i = 0; i < 128; i++)
      Wp[i * 128 + tid] = l1w[i * 128 + tid] + l1w[16384 + i * 128 + tid];
  }
}

// ---------------------------------------------------------------------------
// K4a: softmax over 32 neighbor scores + fp8 weighted row gather -> agg[b][128]
// One half-wave (32 lanes) per b; lane t covers cols 4t..4t+3 (one uint = 4 fp8).
// No LDS, no barriers; att/n broadcast via width-32 shuffles.
// Scores (q, adj, cs) stay fp32 -> att bit-identical to fp32 version; only the
// gather term (<1% of agg magnitude) is quantized.
// ---------------------------------------------------------------------------
__global__ __launch_bounds__(256) void k4a_attn(const unsigned char* __restrict__ fe8,
    const float* __restrict__ q, const float* __restrict__ adj,
    const int* __restrict__ history, const float* __restrict__ cs,
    const float* __restrict__ attb_p, const float* __restrict__ ce01,
    float* __restrict__ agg)
{
  const int tid = threadIdx.x;
  const int lane = tid & 63;
  const int wv = tid >> 6;            // 0..3
  const int half = lane >> 5;         // 0,1
  const int t = lane & 31;            // 0..31
  const int b = blockIdx.x * 8 + wv * 2 + half;

  const int n_my = history[b * 32 + t];
  const float a0 = adj[n_my];
  const float a1 = adj[NN + n_my];
  const float sc = q[n_my] + a0 * cs[0] + a1 * cs[1] + attb_p[0];
  float m = sc;
#pragma unroll
  for (int off = 16; off >= 1; off >>= 1) m = fmaxf(m, __shfl_xor(m, off, 32));
  const float e = expf(sc - m);
  float sum = e;
#pragma unroll
  for (int off = 16; off >= 1; off >>= 1) sum += __shfl_xor(sum, off, 32);
  const float att = e / sum;
  float p0 = att * a0, p1 = att * a1;
#pragma unroll
  for (int off = 16; off >= 1; off >>= 1) {
    p0 += __shfl_xor(p0, off, 32);    // butterfly: all lanes end with full sum
    p1 += __shfl_xor(p1, off, 32);
  }

  float4 acc = make_float4(0.f, 0.f, 0.f, 0.f);
#pragma unroll
  for (int k = 0; k < 32; k++) {
    const int nk = __shfl(n_my, k, 32);
    const float ak = __shfl(att, k, 32);
    const unsigned u = *reinterpret_cast<const unsigned*>(&fe8[(size_t)nk * 128 + t * 4]);
    const floatx2 lo = __builtin_amdgcn_cvt_pk_f32_fp8(u, false);
    const floatx2 hi = __builtin_amdgcn_cvt_pk_f32_fp8(u, true);
    acc.x = fmaf(ak, lo[0], acc.x);
    acc.y = fmaf(ak, lo[1], acc.y);
    acc.z = fmaf(ak, hi[0], acc.z);
    acc.w = fmaf(ak, hi[1], acc.w);
  }
  const int col = t * 4;
  const float4 c0 = *reinterpret_cast<const float4*>(&ce01[col]);
  const float4 c1 = *reinterpret_cast<const float4*>(&ce01[128 + col]);
  float4 o;
  o.x = 0.5f * (acc.x + p0 * c0.x + p1 * c1.x);
  o.y = 0.5f * (acc.y + p0 * c0.y + p1 * c1.y);
  o.z = 0.5f * (acc.z + p0 * c0.z + p1 * c1.z);
  o.w = 0.5f * (acc.w + p0 * c0.w + p1 * c1.w);
  *reinterpret_cast<float4*>(&agg[(size_t)b * 128 + col]) = o;
}

// K4b: out = relu(agg @ Wp + l1b); pred_r/pred_n = dot(latTab rows, out)
__global__ __launch_bounds__(256) void k4b_out(const float* __restrict__ agg,
    const float* __restrict__ Wp, const float* __restrict__ l1b,
    const float* __restrict__ latTab,
    const int* __restrict__ cr, const int* __restrict__ cn, const int* __restrict__ pa,
    float* __restrict__ out)
{
  __shared__ __align__(16) float AT[64][128];
  __shared__ __align__(16) float WT[64][128];
  const int tid = threadIdx.x;
  const int tx = tid & 15, ty = tid >> 4;
  const int rowbase = blockIdx.x * 128;
  float acc[8][8];
  gemm_main<2>(agg, 128, BB - 1, Wp, rowbase, tid, AT, WT, acc);

  int* latIdx = reinterpret_cast<int*>(&AT[0][0]);
  if (tid < 128) {
    const int b = rowbase + tid;
    latIdx[tid * 2]     = (cr[b] * 10 + pa[b]) * 128;
    latIdx[tid * 2 + 1] = (cn[b] * 10 + pa[b]) * 128;
  }
  __syncthreads();

  const float4 b0 = *reinterpret_cast<const float4*>(&l1b[tx * 4]);
  const float4 b1 = *reinterpret_cast<const float4*>(&l1b[tx * 4 + 64]);
  const float bb[8] = {b0.x, b0.y, b0.z, b0.w, b1.x, b1.y, b1.z, b1.w};
#pragma unroll
  for (int i = 0; i < 8; i++) {
    const int r = (i < 4) ? (ty * 4 + i) : (64 + ty * 4 + (i - 4));
    const int b = rowbase + r;
    const int ir = latIdx[r * 2], in_ = latIdx[r * 2 + 1];
    const float4 lr0 = *reinterpret_cast<const float4*>(&latTab[ir + tx * 4]);
    const float4 lr1 = *reinterpret_cast<const float4*>(&latTab[ir + tx * 4 + 64]);
    const float4 ln0 = *reinterpret_cast<const float4*>(&latTab[in_ + tx * 4]);
    const float4 ln1 = *reinterpret_cast<const float4*>(&latTab[in_ + tx * 4 + 64]);
    const float lr[8] = {lr0.x, lr0.y, lr0.z, lr0.w, lr1.x, lr1.y, lr1.z, lr1.w};
    const float ln[8] = {ln0.x, ln0.y, ln0.z, ln0.w, ln1.x, ln1.y, ln1.z, ln1.w};
    float pr = 0.f, pn = 0.f;
#pragma unroll
    for (int j = 0; j < 8; j++) {
      const float v = fmaxf(acc[i][j] + bb[j], 0.f);
      pr = fmaf(v, lr[j], pr);
      pn = fmaf(v, ln[j], pn);
    }
    pr += __shfl_down(pr, 8, 16); pr += __shfl_down(pr, 4, 16);
    pr += __shfl_down(pr, 2, 16); pr += __shfl_down(pr, 1, 16);
    pn += __shfl_down(pn, 8, 16); pn += __shfl_down(pn, 4, 16);
    pn += __shfl_down(pn, 2, 16); pn += __shfl_down(pn, 1, 16);
    if (tx == 0) { out[b] = pr; out[BB + b] = pn; }
  }
}

extern "C" void kernel_launch(void* const* d_in, const int* in_sizes, int n_in,
                              void* d_out, int out_size, void* d_ws, size_t ws_size,
                              hipStream_t stream) {
  const float* feat  = (const float*)d_in[0];   // [N,F]
  const float* adj   = (const float*)d_in[1];   // [M,N]
  const int*   hist  = (const int*)d_in[2];     // [B,K]
  // d_in[3] item_id unused by reference
  const int*   cr    = (const int*)d_in[4];
  const int*   cn    = (const int*)d_in[5];
  const int*   pa    = (const int*)d_in[6];
  const float* wemb  = (const float*)d_in[7];   // [F,D]
  const float* bemb  = (const float*)d_in[8];   // [D]
  const float* wchar = (const float*)d_in[9];   // [2D,D]
  const float* attw  = (const float*)d_in[10];  // [D]
  const float* attb  = (const float*)d_in[11];  // [1]
  const float* l1w   = (const float*)d_in[12];  // [2D,D]
  const float* l1b   = (const float*)d_in[13];  // [D]
  float* out = (float*)d_out;
  float* ws  = (float*)d_ws;

  float* fe   = ws + OFF_FE;
  float* q    = ws + OFF_Q;
  float* part = ws + OFF_PART;
  short* wf   = (short*)(ws + OFF_PART);        // aliased; dead before k2 writes part
  float* lat  = ws + OFF_LAT;
  float* Wp   = ws + OFF_WP;
  float* ce01 = ws + OFF_CE01;
  float* cs   = ws + OFF_CS;
  float* agg  = ws + OFF_AGG;
  unsigned char* fe8 = (unsigned char*)(ws + OFF_FE8);

  k0_wprep<<<16, 256, 0, stream>>>(wemb, wf);
  k1_mfma<<<782, 256, 0, stream>>>(feat, wf, bemb, attw, fe, q, fe8);
  k2_char<<<256, 512, 0, stream>>>(fe, adj, part);
  k3_prep<<<21, 128, 0, stream>>>(part, wchar, attw, l1w, lat, Wp, ce01, cs);
  k4a_attn<<<4096, 256, 0, stream>>>(fe8, q, adj, hist, cs, attb, ce01, agg);
  k4b_out<<<256, 256, 0, stream>>>(agg, Wp, l1b, lat, cr, cn, pa, out);
}